// Round 3
// baseline (312.881 us; speedup 1.0000x reference)
//
#include <hip/hip_runtime.h>
#include <float.h>

#define NN 50000
#define NE 800000
#define FD 64
#define NG 64
#define SCAN_B 256
#define NBLK ((NN + SCAN_B - 1) / SCAN_B)   // 196

// ---------- monotonic float<->uint encoding for atomic max ----------
__device__ inline unsigned encf(float f) {
    unsigned u = __float_as_uint(f);
    return (u & 0x80000000u) ? ~u : (u | 0x80000000u);
}
__device__ inline float decf(unsigned e) {
    unsigned u = (e & 0x80000000u) ? (e ^ 0x80000000u) : ~e;
    return __uint_as_float(u);
}

// ---------- init: cnt = 0, gmax = enc(-inf) ----------
__global__ void k_init(int* __restrict__ cnt, unsigned* __restrict__ gmax) {
    int i = blockIdx.x * blockDim.x + threadIdx.x;
    if (i < NN) cnt[i] = 0;
    if (i < NG * FD) gmax[i] = encf(-FLT_MAX);
}

__global__ void k_cnt(const int* __restrict__ dst, int* __restrict__ cnt) {
    int i = blockIdx.x * blockDim.x + threadIdx.x;
    if (i < NE) atomicAdd(&cnt[dst[i]], 1);
}

__global__ void k_dis(const int* __restrict__ cnt, float* __restrict__ dis) {
    int i = blockIdx.x * blockDim.x + threadIdx.x;
    if (i < NN) dis[i] = rsqrtf((float)cnt[i] + 1.0f);  // +1 = self loop
}

// ---------- pre-scale: Xsc[r,:] = dis[r] * X[r,:] ----------
__global__ void k_prep(const float* __restrict__ X, const float* __restrict__ dis,
                       float* __restrict__ Xsc) {
    int t = blockIdx.x * blockDim.x + threadIdx.x;
    if (t < NN * FD) Xsc[t] = X[t] * dis[t >> 6];
}

// ---------- exclusive scan of cnt -> rp ----------
__global__ void k_scan1(const int* __restrict__ cnt, int* __restrict__ rp,
                        int* __restrict__ bsum) {
    __shared__ int tmp[SCAN_B];
    int b = blockIdx.x, t = threadIdx.x;
    int i = b * SCAN_B + t;
    int v = (i < NN) ? cnt[i] : 0;
    tmp[t] = v;
    __syncthreads();
    for (int off = 1; off < SCAN_B; off <<= 1) {
        int add = (t >= off) ? tmp[t - off] : 0;
        __syncthreads();
        tmp[t] += add;
        __syncthreads();
    }
    if (i < NN) rp[i] = tmp[t] - v;
    if (t == SCAN_B - 1) bsum[b] = tmp[t];
}

__global__ void k_scan2(int* __restrict__ bsum) {
    __shared__ int tmp[256];
    int t = threadIdx.x;
    int v = (t < NBLK) ? bsum[t] : 0;
    tmp[t] = v;
    __syncthreads();
    for (int off = 1; off < 256; off <<= 1) {
        int add = (t >= off) ? tmp[t - off] : 0;
        __syncthreads();
        tmp[t] += add;
        __syncthreads();
    }
    if (t < NBLK) bsum[t] = tmp[t] - v;
}

__global__ void k_scan3(int* __restrict__ rp, const int* __restrict__ bsum,
                        int* __restrict__ cnt) {
    int i = blockIdx.x * blockDim.x + threadIdx.x;
    if (i < NN) {
        rp[i] += bsum[i / SCAN_B];
        cnt[i] = 0;                           // becomes fill cursor
    }
    if (i == 0) rp[NN] = NE;
}

__global__ void k_fill(const int* __restrict__ src, const int* __restrict__ dst,
                       const int* __restrict__ rp, int* __restrict__ cur,
                       int* __restrict__ esrc) {
    int e = blockIdx.x * blockDim.x + threadIdx.x;
    if (e < NE) {
        int d = dst[e];
        int p = rp[d] + atomicAdd(&cur[d], 1);
        esrc[p] = src[e];
    }
}

// ---------- fused gather + row-GEMM ----------
// acc = Hs[d,:] + sum_{s in N(d)} Hs[s,:]      (Hs rows pre-scaled by dis)
// g   = dis[d] * acc
// o   = g @ W + bias                            (row GEMM via shfl, W in LDS)
// MODE 0: Rout[d,:] = dis[d] * relu(o)          (pre-scaled for next layer)
// MODE 1: gmax[batch[d],:] = max(., o)
template<int MODE>
__global__ __launch_bounds__(256) void k_gather_mm(const int* __restrict__ rp,
                                                   const int* __restrict__ esrc,
                                                   const float* __restrict__ dis,
                                                   const float* __restrict__ Hs,
                                                   const float* __restrict__ W,
                                                   const float* __restrict__ bias,
                                                   float* __restrict__ Rout,
                                                   const int* __restrict__ batch,
                                                   unsigned* __restrict__ gmax) {
    __shared__ float Ws[64 * 64];
    for (int i = threadIdx.x; i < 64 * 64; i += 256) Ws[i] = W[i];
    __syncthreads();
    int gtid  = blockIdx.x * blockDim.x + threadIdx.x;
    int wave  = gtid >> 6;
    int lane  = threadIdx.x & 63;
    int nwave = (gridDim.x * blockDim.x) >> 6;
    for (int d = wave; d < NN; d += nwave) {
        int beg = rp[d], end = rp[d + 1];
        float a0 = Hs[d * FD + lane];   // self-loop (pre-scaled)
        float a1 = 0.f, a2 = 0.f, a3 = 0.f, a4 = 0.f, a5 = 0.f, a6 = 0.f, a7 = 0.f;
        int j = beg;
        for (; j + 8 <= end; j += 8) {
            int s0 = esrc[j],     s1 = esrc[j + 1], s2 = esrc[j + 2], s3 = esrc[j + 3];
            int s4 = esrc[j + 4], s5 = esrc[j + 5], s6 = esrc[j + 6], s7 = esrc[j + 7];
            a0 += Hs[s0 * FD + lane];
            a1 += Hs[s1 * FD + lane];
            a2 += Hs[s2 * FD + lane];
            a3 += Hs[s3 * FD + lane];
            a4 += Hs[s4 * FD + lane];
            a5 += Hs[s5 * FD + lane];
            a6 += Hs[s6 * FD + lane];
            a7 += Hs[s7 * FD + lane];
        }
        for (; j < end; ++j) a0 += Hs[esrc[j] * FD + lane];
        float dd = dis[d];
        float g = dd * (((a0 + a1) + (a2 + a3)) + ((a4 + a5) + (a6 + a7)));
        // row GEMM: o[lane] = bias[lane] + sum_k g_k * Ws[k,lane]
        float o = bias[lane];
#pragma unroll
        for (int k = 0; k < 64; ++k) {
            float gk = __shfl(g, k);
            o = fmaf(gk, Ws[k * 64 + lane], o);
        }
        if (MODE == 0) {
            Rout[d * FD + lane] = dd * fmaxf(o, 0.0f);
        } else {
            atomicMax(&gmax[batch[d] * FD + lane], encf(o));
        }
    }
}

// ---------- final: out[g,c] = sum_f gmax[g,f] * Wlin[f,c] + blin[c] ----------
__global__ __launch_bounds__(128) void k_final(const unsigned* __restrict__ gmax,
                                               const float* __restrict__ Wlin,
                                               const float* __restrict__ blin,
                                               float* __restrict__ out) {
    __shared__ float G[NG * FD];
    for (int i = threadIdx.x; i < NG * FD; i += 128) G[i] = decf(gmax[i]);
    __syncthreads();
    int t = threadIdx.x;
    int g = t >> 1, c = t & 1;
    float acc = blin[c];
#pragma unroll
    for (int f = 0; f < 64; ++f) acc = fmaf(G[g * 64 + f], Wlin[f * 2 + c], acc);
    out[g * 2 + c] = acc;
}

extern "C" void kernel_launch(void* const* d_in, const int* in_sizes, int n_in,
                              void* d_out, int out_size, void* d_ws, size_t ws_size,
                              hipStream_t stream) {
    const float* x     = (const float*)d_in[0];
    const int*   eidx  = (const int*)d_in[1];
    const int*   batch = (const int*)d_in[2];
    const float* W1    = (const float*)d_in[3];
    const float* b1    = (const float*)d_in[4];
    const float* W2    = (const float*)d_in[5];
    const float* b2    = (const float*)d_in[6];
    const float* Wlin  = (const float*)d_in[7];
    const float* blin  = (const float*)d_in[8];
    float* out = (float*)d_out;

    const int* src = eidx;
    const int* dst = eidx + NE;

    char* ws = (char*)d_ws;
    size_t off = 0;
    auto alloc = [&](size_t bytes) { char* p = ws + off; off += (bytes + 255) & ~size_t(255); return p; };
    int*      cnt  = (int*)alloc(NN * 4);
    float*    dis  = (float*)alloc(NN * 4);
    int*      rp   = (int*)alloc((NN + 1) * 4);
    int*      bsum = (int*)alloc(NBLK * 4);
    int*      esrc = (int*)alloc(NE * 4);                   // 3.2 MB
    unsigned* gmax = (unsigned*)alloc(NG * FD * 4);
    float*    Xsc  = (float*)alloc((size_t)NN * FD * 4);    // 12.8 MB
    float*    R    = (float*)alloc((size_t)NN * FD * 4);    // 12.8 MB

    const int B = 256;
    const int gN  = (NN + B - 1) / B;
    const int gE  = (NE + B - 1) / B;
    const int gNF = (NN * FD + B - 1) / B;
    const int gatherBlocks = 2048;   // 8192 waves (max resident), ~6 rows each

    // ---- CSR build + norm + pre-scale ----
    k_init<<<gN, B, 0, stream>>>(cnt, gmax);
    k_cnt<<<gE, B, 0, stream>>>(dst, cnt);
    k_dis<<<gN, B, 0, stream>>>(cnt, dis);
    k_prep<<<gNF, B, 0, stream>>>(x, dis, Xsc);
    k_scan1<<<NBLK, SCAN_B, 0, stream>>>(cnt, rp, bsum);
    k_scan2<<<1, 256, 0, stream>>>(bsum);
    k_scan3<<<gN, B, 0, stream>>>(rp, bsum, cnt);
    k_fill<<<gE, B, 0, stream>>>(src, dst, rp, cnt, esrc);

    // ---- layer 1 fused: R = dis * relu(gather(Xsc) @ W1 + b1) ----
    k_gather_mm<0><<<gatherBlocks, B, 0, stream>>>(rp, esrc, dis, Xsc, W1, b1, R, batch, gmax);

    // ---- layer 2 fused: gmax = segmax(gather(R) @ W2 + b2) ----
    k_gather_mm<1><<<gatherBlocks, B, 0, stream>>>(rp, esrc, dis, R, W2, b2, nullptr, batch, gmax);

    // ---- head ----
    k_final<<<1, 128, 0, stream>>>(gmax, Wlin, blin, out);
}

// Round 4
// 226.921 us; speedup vs baseline: 1.3788x; 1.3788x over previous
//
#include <hip/hip_runtime.h>
#include <float.h>

#define NN 50000
#define NE 800000
#define FD 64
#define NG 64
#define SCAN_B 256
#define NBLK ((NN + SCAN_B - 1) / SCAN_B)   // 196

typedef __attribute__((ext_vector_type(8))) short short8;
typedef __attribute__((ext_vector_type(8))) float float8;
typedef __attribute__((ext_vector_type(4))) float f32x4;

// ---------- bf16 helpers (RNE) ----------
__device__ inline unsigned short f2bf(float f) {
    unsigned u = __float_as_uint(f);
    u += 0x7fffu + ((u >> 16) & 1u);
    return (unsigned short)(u >> 16);
}
__device__ inline float bf2f(unsigned short h) {
    return __uint_as_float(((unsigned)h) << 16);
}

// ---------- monotonic float<->uint encoding for atomic max ----------
__device__ inline unsigned encf(float f) {
    unsigned u = __float_as_uint(f);
    return (u & 0x80000000u) ? ~u : (u | 0x80000000u);
}
__device__ inline float decf(unsigned e) {
    unsigned u = (e & 0x80000000u) ? (e ^ 0x80000000u) : ~e;
    return __uint_as_float(u);
}

// ---------- init: cnt = 0, gmax = enc(-inf) ----------
__global__ void k_init(int* __restrict__ cnt, unsigned* __restrict__ gmax) {
    int i = blockIdx.x * blockDim.x + threadIdx.x;
    if (i < NN) cnt[i] = 0;
    if (i < NG * FD) gmax[i] = encf(-FLT_MAX);
}

__global__ void k_cnt(const int* __restrict__ dst, int* __restrict__ cnt) {
    int i = blockIdx.x * blockDim.x + threadIdx.x;
    if (i < NE) atomicAdd(&cnt[dst[i]], 1);
}

// ---------- scan1 (+ dis computation folded in) ----------
__global__ void k_scan1(const int* __restrict__ cnt, int* __restrict__ rp,
                        int* __restrict__ bsum, float* __restrict__ dis) {
    __shared__ int tmp[SCAN_B];
    int b = blockIdx.x, t = threadIdx.x;
    int i = b * SCAN_B + t;
    int v = (i < NN) ? cnt[i] : 0;
    if (i < NN) dis[i] = rsqrtf((float)v + 1.0f);   // +1 self loop
    tmp[t] = v;
    __syncthreads();
    for (int off = 1; off < SCAN_B; off <<= 1) {
        int add = (t >= off) ? tmp[t - off] : 0;
        __syncthreads();
        tmp[t] += add;
        __syncthreads();
    }
    if (i < NN) rp[i] = tmp[t] - v;
    if (t == SCAN_B - 1) bsum[b] = tmp[t];
}

__global__ void k_scan2(int* __restrict__ bsum) {
    __shared__ int tmp[256];
    int t = threadIdx.x;
    int v = (t < NBLK) ? bsum[t] : 0;
    tmp[t] = v;
    __syncthreads();
    for (int off = 1; off < 256; off <<= 1) {
        int add = (t >= off) ? tmp[t - off] : 0;
        __syncthreads();
        tmp[t] += add;
        __syncthreads();
    }
    if (t < NBLK) bsum[t] = tmp[t] - v;
}

__global__ void k_scan3(int* __restrict__ rp, const int* __restrict__ bsum,
                        int* __restrict__ cnt) {
    int i = blockIdx.x * blockDim.x + threadIdx.x;
    if (i < NN) {
        rp[i] += bsum[i / SCAN_B];
        cnt[i] = 0;                           // becomes fill cursor
    }
    if (i == 0) rp[NN] = NE;
}

__global__ void k_fill(const int* __restrict__ src, const int* __restrict__ dst,
                       const int* __restrict__ rp, int* __restrict__ cur,
                       int* __restrict__ esrc) {
    int e = blockIdx.x * blockDim.x + threadIdx.x;
    if (e < NE) {
        int d = dst[e];
        int p = rp[d] + atomicAdd(&cur[d], 1);
        esrc[p] = src[e];
    }
}

// ---------- MFMA GEMM: Hs[r,:] = dis[r] * (X[r,:] @ W) ----------
// bf16 hi/lo split, 3 products -> ~f32 precision. 16x16x32 MFMA.
// Wave tile: 16 rows x 64 cols. A: row = lane&15, k = (lane>>4)*8 + j.
// B (=W^T staged in LDS): col = lane&15, same k map -> any consistent k
// bijection is correct. D: row = (lane>>4)*4 + r, col = lane&15 [verified].
__global__ __launch_bounds__(256) void k_gemm_mfma(const float* __restrict__ X,
                                                   const float* __restrict__ W,
                                                   const float* __restrict__ dis,
                                                   float* __restrict__ Hs) {
    __shared__ unsigned short WtHi[4096];
    __shared__ unsigned short WtLo[4096];
    for (int i = threadIdx.x; i < 4096; i += 256) {
        int k = i >> 6, n = i & 63;
        float w = W[i];                        // W[k][n]
        unsigned short hi = f2bf(w);
        WtHi[n * 64 + k] = hi;
        WtLo[n * 64 + k] = f2bf(w - bf2f(hi));
    }
    __syncthreads();
    int lane = threadIdx.x & 63;
    int m  = lane & 15;    // A-row / D-col
    int kg = lane >> 4;    // k group
    short8 bh[4][2], bl[4][2];
#pragma unroll
    for (int t = 0; t < 4; ++t)
#pragma unroll
        for (int c = 0; c < 2; ++c) {
            int n  = 16 * t + m;
            int k0 = 32 * c + kg * 8;
            bh[t][c] = *(const short8*)&WtHi[n * 64 + k0];
            bl[t][c] = *(const short8*)&WtLo[n * 64 + k0];
        }
    int wid = (blockIdx.x * blockDim.x + threadIdx.x) >> 6;
    int nw  = (gridDim.x * blockDim.x) >> 6;
    for (int tile = wid; tile < NN / 16; tile += nw) {   // NN = 16*3125 exactly
        int r0 = tile * 16;
        f32x4 z = {0.f, 0.f, 0.f, 0.f};
        f32x4 acc0 = z, acc1 = z, acc2 = z, acc3 = z;
#pragma unroll
        for (int c = 0; c < 2; ++c) {
            float8 xv = *(const float8*)(X + (size_t)(r0 + m) * FD + 32 * c + kg * 8);
            short8 ah, al;
#pragma unroll
            for (int j = 0; j < 8; ++j) {
                unsigned short hi = f2bf(xv[j]);
                ah[j] = (short)hi;
                al[j] = (short)f2bf(xv[j] - bf2f(hi));
            }
            acc0 = __builtin_amdgcn_mfma_f32_16x16x32_bf16(ah, bh[0][c], acc0, 0, 0, 0);
            acc0 = __builtin_amdgcn_mfma_f32_16x16x32_bf16(ah, bl[0][c], acc0, 0, 0, 0);
            acc0 = __builtin_amdgcn_mfma_f32_16x16x32_bf16(al, bh[0][c], acc0, 0, 0, 0);
            acc1 = __builtin_amdgcn_mfma_f32_16x16x32_bf16(ah, bh[1][c], acc1, 0, 0, 0);
            acc1 = __builtin_amdgcn_mfma_f32_16x16x32_bf16(ah, bl[1][c], acc1, 0, 0, 0);
            acc1 = __builtin_amdgcn_mfma_f32_16x16x32_bf16(al, bh[1][c], acc1, 0, 0, 0);
            acc2 = __builtin_amdgcn_mfma_f32_16x16x32_bf16(ah, bh[2][c], acc2, 0, 0, 0);
            acc2 = __builtin_amdgcn_mfma_f32_16x16x32_bf16(ah, bl[2][c], acc2, 0, 0, 0);
            acc2 = __builtin_amdgcn_mfma_f32_16x16x32_bf16(al, bh[2][c], acc2, 0, 0, 0);
            acc3 = __builtin_amdgcn_mfma_f32_16x16x32_bf16(ah, bh[3][c], acc3, 0, 0, 0);
            acc3 = __builtin_amdgcn_mfma_f32_16x16x32_bf16(ah, bl[3][c], acc3, 0, 0, 0);
            acc3 = __builtin_amdgcn_mfma_f32_16x16x32_bf16(al, bh[3][c], acc3, 0, 0, 0);
        }
        float dd[4];
#pragma unroll
        for (int r = 0; r < 4; ++r) dd[r] = dis[r0 + kg * 4 + r];
#pragma unroll
        for (int r = 0; r < 4; ++r) {
            size_t row = (size_t)(r0 + kg * 4 + r) * FD;
            Hs[row + 16 * 0 + m] = dd[r] * acc0[r];
            Hs[row + 16 * 1 + m] = dd[r] * acc1[r];
            Hs[row + 16 * 2 + m] = dd[r] * acc2[r];
            Hs[row + 16 * 3 + m] = dd[r] * acc3[r];
        }
    }
}

// ---------- gather aggregation (rows pre-scaled by dis) ----------
// v = dis[d] * (Hs[d,:] + sum_{s in N(d)} Hs[s,:]) + bias
// MODE 0: O[d,:] = relu(v)   MODE 1: gmax[batch[d],:] = max(., v)
template<int MODE>
__global__ __launch_bounds__(256) void k_gather(const int* __restrict__ rp,
                                                const int* __restrict__ esrc,
                                                const float* __restrict__ dis,
                                                const float* __restrict__ Hs,
                                                const float* __restrict__ bias,
                                                float* __restrict__ O,
                                                const int* __restrict__ batch,
                                                unsigned* __restrict__ gmax) {
    int gtid  = blockIdx.x * blockDim.x + threadIdx.x;
    int wave  = gtid >> 6;
    int lane  = threadIdx.x & 63;
    int nwave = (gridDim.x * blockDim.x) >> 6;
    for (int d = wave; d < NN; d += nwave) {
        int beg = rp[d], end = rp[d + 1];
        float a0 = Hs[(size_t)d * FD + lane];   // self-loop (pre-scaled)
        float a1 = 0.f, a2 = 0.f, a3 = 0.f, a4 = 0.f, a5 = 0.f, a6 = 0.f, a7 = 0.f;
        int j = beg;
        for (; j + 8 <= end; j += 8) {
            int s0 = esrc[j],     s1 = esrc[j + 1], s2 = esrc[j + 2], s3 = esrc[j + 3];
            int s4 = esrc[j + 4], s5 = esrc[j + 5], s6 = esrc[j + 6], s7 = esrc[j + 7];
            a0 += Hs[(size_t)s0 * FD + lane];
            a1 += Hs[(size_t)s1 * FD + lane];
            a2 += Hs[(size_t)s2 * FD + lane];
            a3 += Hs[(size_t)s3 * FD + lane];
            a4 += Hs[(size_t)s4 * FD + lane];
            a5 += Hs[(size_t)s5 * FD + lane];
            a6 += Hs[(size_t)s6 * FD + lane];
            a7 += Hs[(size_t)s7 * FD + lane];
        }
        for (; j < end; ++j) a0 += Hs[(size_t)esrc[j] * FD + lane];
        float v = dis[d] * (((a0 + a1) + (a2 + a3)) + ((a4 + a5) + (a6 + a7))) + bias[lane];
        if (MODE == 0) {
            O[(size_t)d * FD + lane] = fmaxf(v, 0.0f);
        } else {
            atomicMax(&gmax[batch[d] * FD + lane], encf(v));
        }
    }
}

// ---------- final: out[g,c] = sum_f gmax[g,f] * Wlin[f,c] + blin[c] ----------
__global__ __launch_bounds__(128) void k_final(const unsigned* __restrict__ gmax,
                                               const float* __restrict__ Wlin,
                                               const float* __restrict__ blin,
                                               float* __restrict__ out) {
    __shared__ float G[NG * FD];
    for (int i = threadIdx.x; i < NG * FD; i += 128) G[i] = decf(gmax[i]);
    __syncthreads();
    int t = threadIdx.x;
    int g = t >> 1, c = t & 1;
    float acc = blin[c];
#pragma unroll
    for (int f = 0; f < 64; ++f) acc = fmaf(G[g * 64 + f], Wlin[f * 2 + c], acc);
    out[g * 2 + c] = acc;
}

extern "C" void kernel_launch(void* const* d_in, const int* in_sizes, int n_in,
                              void* d_out, int out_size, void* d_ws, size_t ws_size,
                              hipStream_t stream) {
    const float* x     = (const float*)d_in[0];
    const int*   eidx  = (const int*)d_in[1];
    const int*   batch = (const int*)d_in[2];
    const float* W1    = (const float*)d_in[3];
    const float* b1    = (const float*)d_in[4];
    const float* W2    = (const float*)d_in[5];
    const float* b2    = (const float*)d_in[6];
    const float* Wlin  = (const float*)d_in[7];
    const float* blin  = (const float*)d_in[8];
    float* out = (float*)d_out;

    const int* src = eidx;
    const int* dst = eidx + NE;

    char* ws = (char*)d_ws;
    size_t off = 0;
    auto alloc = [&](size_t bytes) { char* p = ws + off; off += (bytes + 255) & ~size_t(255); return p; };
    int*      cnt  = (int*)alloc(NN * 4);
    float*    dis  = (float*)alloc(NN * 4);
    int*      rp   = (int*)alloc((NN + 1) * 4);
    int*      bsum = (int*)alloc(NBLK * 4);
    int*      esrc = (int*)alloc(NE * 4);                   // 3.2 MB
    unsigned* gmax = (unsigned*)alloc(NG * FD * 4);
    float*    Hs   = (float*)alloc((size_t)NN * FD * 4);    // 12.8 MB
    float*    O    = (float*)alloc((size_t)NN * FD * 4);    // 12.8 MB

    const int B = 256;
    const int gN = (NN + B - 1) / B;
    const int gE = (NE + B - 1) / B;
    const int gemmBlocks   = 512;    // 2048 waves, 1-2 row-tiles each
    const int gatherBlocks = 2048;   // 8192 waves

    // ---- CSR build + norm ----
    k_init<<<gN, B, 0, stream>>>(cnt, gmax);
    k_cnt<<<gE, B, 0, stream>>>(dst, cnt);
    k_scan1<<<NBLK, SCAN_B, 0, stream>>>(cnt, rp, bsum, dis);
    k_scan2<<<1, 256, 0, stream>>>(bsum);
    k_scan3<<<gN, B, 0, stream>>>(rp, bsum, cnt);
    k_fill<<<gE, B, 0, stream>>>(src, dst, rp, cnt, esrc);

    // ---- layer 1: Hs = dis * (x @ W1) ; O = relu(gather(Hs) + b1) ----
    k_gemm_mfma<<<gemmBlocks, B, 0, stream>>>(x, W1, dis, Hs);
    k_gather<0><<<gatherBlocks, B, 0, stream>>>(rp, esrc, dis, Hs, b1, O, batch, gmax);

    // ---- layer 2: Hs = dis * (O @ W2) ; gmax = segmax(gather(Hs) + b2) ----
    k_gemm_mfma<<<gemmBlocks, B, 0, stream>>>(O, W2, dis, Hs);
    k_gather<1><<<gatherBlocks, B, 0, stream>>>(rp, esrc, dis, Hs, b2, nullptr, batch, gmax);

    // ---- head ----
    k_final<<<1, 128, 0, stream>>>(gmax, Wlin, blin, out);
}